// Round 12
// baseline (1407.122 us; speedup 1.0000x reference)
//
#include <hip/hip_runtime.h>

#define S_ROWS 16384
#define T_ROWS 32768
#define NROWS  49152
#define DDIM   4096
#define C      21
#define KSPLIT 4
#define RPB    256                     // rows per block (64 lanes x 4 rows/lane)

// workspace layout (in floats)
#define WT_OFF 0
#define WT_SZ  (C * DDIM)              // 86016: W transposed to [C][D]
#define P_OFF  (WT_OFF + WT_SZ)
#define P_SLOT (NROWS * C)             // 1032192 per k-slot
#define DM_OFF (P_OFF + KSPLIT * P_SLOT)
#define N_OFF  (DM_OFF + C)
#define NW_OFF (N_OFF + C)

// LDS layout for k_gemm (floats): double-buffered X + W tiles, TILE_K=16
// X tile: 256 rows x 16 k = 4096 floats; W tile: 32 rows x 16 = 512 floats
#define XB0 0
#define XB1 4096
#define WB0 8192
#define WB1 (8192 + 512)
#define SMEM_FL 10752                  // 43008 B (reduction needs 10752 fl)

// ---------------- kernel 1: transpose W, zero accumulators ----------------
__global__ void k_prep(const float* __restrict__ W, float* __restrict__ ws) {
    int idx = blockIdx.x * 256 + threadIdx.x;
    if (idx < C * DDIM) {
        int c = idx / DDIM, d = idx - c * DDIM;
        ws[WT_OFF + idx] = W[d * C + c];
    }
    if (blockIdx.x == 0 && threadIdx.x < 2 * C) {
        ws[DM_OFF + threadIdx.x] = 0.0f;   // zeroes delta_margin[21] + num[21]
    }
}

// async 16B global->LDS DMA (zero VGPR round-trip; lds dest = wave base + lane*16)
typedef const __attribute__((address_space(1))) void* gas_ptr;
typedef __attribute__((address_space(3))) void* las_ptr;
__device__ __forceinline__ void gload_lds16(const float* g, float* l) {
    __builtin_amdgcn_global_load_lds((gas_ptr)g, (las_ptr)l, 16, 0, 0);
}

// ---------------- kernel 2: tiled GEMM partials -------------------------
// block: 256 threads = 4 waves; 256 rows/block; grid (192 row-groups, 4 k-chunks)
// = 768 blocks = EXACTLY 3 blocks/CU, one round, no tail.
// TILE_K=16: wave w owns the 4-wide k-slot w of each 16-wide k-tile; lane l
// owns rows l + r*64, r=0..3. acc[4][21] in registers; W broadcast from LDS.
//
// HISTORY / DISCIPLINE (11 rounds of evidence):
//  - EXECUTION SHAPE IS LOAD-BEARING: R5 (3 blocks/CU, exact 1 round, depth-1
//    __syncthreads dbuf) ran AT its resource model (~190us). Every 2-block/CU
//    or 1.5-round variant (R4 370, R11 337) ran 2-3x ABOVE model even in
//    steady state; 1 wave/SIMD (R9) and 512-thread blocks (R10 spill) worse.
//    Counted-vmcnt at 3 blocks/CU: NULL (R6). W-via-global: regress (R7).
//  - R5's cost breakdown: 42 of 46 b128/wave-iter are broadcast W reads
//    (LDS 177us >> HBM 148us). Lever = rows/lane (W amortization).
//  - R12 (this): keep R5's shape EXACTLY (3 blocks/CU x 768 blocks, 64 iters,
//    4 waves, depth-1 sync dbuf), raise rows/lane to 4 via TILE_K=16:
//    25 b128/wave-iter for the same FMA count -> LDS 1.5us/CU-slot under
//    HBM 2.18us -> HBM-bound ~150us. acc[4][21]=84 regs (proven no-spill);
//    LDS 43008B x 3 = 129KB; launch_bounds(256,3) cap 168 vs ~140 live.
//  - XOR swizzle for 16-fl rows (rule 21 both-sides): physical slot =
//    logical ^ x(row), x(row) = (row>>1)&3. DMA source pre-XORs
//    (l&3)^((l>>3)&3) (same 64B row-segment per 4-lane quad -> coalesced);
//    compute reads slot w ^ ((l>>1)&3) (r*64 doesn't change it). Verified
//    involution both directions.
//  - src/tgt selected PER 16-ROW DMA GROUP (R8 lesson): 16-aligned ranges
//    cannot straddle the 16384 boundary.
__launch_bounds__(256, 3)
__global__ void k_gemm(const float* __restrict__ src, const float* __restrict__ tgt,
                       float* __restrict__ ws) {
    __shared__ float smem[SMEM_FL];
    const int tid = threadIdx.x;
    const int g   = blockIdx.x;             // row group (256 rows)
    const int ks  = blockIdx.y;             // k chunk (1024 d)
    const int l   = tid & 63, w = tid >> 6;
    const int rg0 = g * RPB;
    const float* wt = ws + WT_OFF;

    // X DMA: 4 ops/wave, op i covers 16 rows starting at w*64 + i*16.
    // lane l -> local row l>>2, slot l&3; source pre-swizzled by (l>>3)&3.
    const int rr  = l >> 2, s4 = l & 3;
    const int fsw = ((s4 ^ ((l >> 3) & 3)) << 2);   // float offset in row
    const float* xg[4];
#pragma unroll
    for (int i = 0; i < 4; ++i) {
        const int grow = rg0 + w * 64 + i * 16;     // 16-row group start
        const float* bp = (grow < S_ROWS)
            ? (src + (size_t)grow * DDIM)
            : (tgt + (size_t)(grow - S_ROWS) * DDIM);
        xg[i] = bp + (size_t)rr * DDIM + ks * 1024 + fsw;
    }
    // W DMA: waves 0,1 each stage 16 rows (rows 21..31 read harmless ws bytes)
    const float* wg = wt + (size_t)(w * 16 + rr) * DDIM + ks * 1024 + (s4 << 2);

    float acc[4][C];
#pragma unroll
    for (int r = 0; r < 4; ++r)
#pragma unroll
        for (int c = 0; c < C; ++c) acc[r][c] = 0.0f;

    // prologue: stage tile 0 into buffer 0
#pragma unroll
    for (int i = 0; i < 4; ++i)
        gload_lds16(xg[i], &smem[XB0 + (w * 64 + i * 16) * 16]);
    if (w < 2) gload_lds16(wg, &smem[WB0 + w * 256]);
    __syncthreads();

    // hoisted compute-read constants
    const int xslot = (w ^ ((l >> 1) & 3)) << 2;    // swizzled slot, lane-const
    const int xbase = l * 16 + xslot;
    const int wslot = w << 2;

#pragma unroll 1
    for (int t = 0; t < 64; ++t) {
        const int xcur = (t & 1) ? XB1 : XB0;
        const int wcur = (t & 1) ? WB1 : WB0;
        // issue DMA for tile t+1 into the other buffer (flies under compute;
        // 3 staggered blocks/CU keep HBM busy through each block's drain)
        if (t < 63) {
            const int xnxt = (t & 1) ? XB0 : XB1;
            const int wnxt = (t & 1) ? WB0 : WB1;
            const int koff = (t + 1) * 16;
#pragma unroll
            for (int i = 0; i < 4; ++i)
                gload_lds16(xg[i] + koff, &smem[xnxt + (w * 64 + i * 16) * 16]);
            if (w < 2) gload_lds16(wg + koff, &smem[wnxt + w * 256]);
        }

        // single 4-wide pass: this wave's k-slot is w
        float4 xr[4];
#pragma unroll
        for (int r = 0; r < 4; ++r)
            xr[r] = *(const float4*)&smem[xcur + xbase + r * 1024];
#pragma unroll
        for (int c = 0; c < C; ++c) {
            float4 wv = *(const float4*)&smem[wcur + c * 16 + wslot];
#pragma unroll
            for (int r = 0; r < 4; ++r) {
                acc[r][c] += xr[r].x * wv.x + xr[r].y * wv.y +
                             xr[r].z * wv.z + xr[r].w * wv.w;
            }
        }
        __syncthreads();   // drains DMA vmcnt + lgkm; one barrier per iter
    }

    // cross-wave reduction (two halves of 128 rows, 10752 fl), store partials;
    // h statically unrolled so acc stays register-indexed (rule #20)
    float* pout = ws + P_OFF + (size_t)ks * P_SLOT;
#pragma unroll
    for (int h = 0; h < 2; ++h) {
#pragma unroll
        for (int c = 0; c < C; ++c) {
            smem[w * 2688 + l * 21 + c]        = acc[2 * h][c];
            smem[w * 2688 + (l + 64) * 21 + c] = acc[2 * h + 1][c];
        }
        __syncthreads();
        for (int idx = tid; idx < 2688; idx += 256) {
            int row = idx / 21, c = idx - row * 21;
            float s = smem[row * 21 + c] + smem[2688 + row * 21 + c] +
                      smem[5376 + row * 21 + c] + smem[8064 + row * 21 + c];
            pout[(size_t)(rg0 + h * 128 + row) * 21 + c] = s;
        }
        __syncthreads();
    }
}

// ---------------- kernel 3: sum partials, softmax, stats ----------------
__global__ void k_phaseB(const float* __restrict__ b_cls, float* __restrict__ ws,
                         float* __restrict__ out) {
    const int tid = threadIdx.x;
    const int row = blockIdx.x * 256 + tid;
    const float* P = ws + P_OFF;
    float lg[C];
#pragma unroll
    for (int c = 0; c < C; ++c) lg[c] = b_cls[c];
    for (int k = 0; k < KSPLIT; ++k) {
        const float* p = P + (size_t)k * P_SLOT + (size_t)row * C;
#pragma unroll
        for (int c = 0; c < C; ++c) lg[c] += p[c];
    }
    float m = lg[0];
#pragma unroll
    for (int c = 1; c < C; ++c) m = fmaxf(m, lg[c]);
    float e[C], s = 0.0f;
#pragma unroll
    for (int c = 0; c < C; ++c) { e[c] = __expf(lg[c] - m); s += e[c]; }
    float inv = 1.0f / s;

    if (row < S_ROWS) {                    // block-uniform branch (64 src blocks)
        float* o = out + (size_t)row * 22;
#pragma unroll
        for (int c = 0; c < C; ++c) o[c] = e[c] * inv;
    } else {
        __shared__ float s_dm[C], s_n[C];
        if (tid < C) { s_dm[tid] = 0.0f; s_n[tid] = 0.0f; }
        __syncthreads();
        float top = -1.0f, sum = 0.0f; int arg = 0;
#pragma unroll
        for (int c = 0; c < C; ++c) {
            float p = e[c] * inv; sum += p;
            if (p > top) { top = p; arg = c; }   // strict > keeps first argmax
        }
        float margin = top - (sum - top) * (1.0f / (C - 1));
        if (arg != 0) {
            atomicAdd(&s_dm[arg], margin);
            atomicAdd(&s_n[arg], 1.0f);
        }
        __syncthreads();
        if (tid < C) {
            atomicAdd(&ws[DM_OFF + tid], s_dm[tid]);
            atomicAdd(&ws[N_OFF + tid], s_n[tid]);
        }
    }
}

// ---------------- kernel 4: blend + minmax normalize (1 block) ----------
__global__ void k_final(const float* __restrict__ tmf, const float* __restrict__ rec,
                        float* __restrict__ ws) {
    __shared__ float wv[C];
    __shared__ float mm[2];
    const int t = threadIdx.x;
    if (t < C) {
        float r = rec[0];
        float n = ws[N_OFF + t];
        float blended = (tmf[t] * r + ws[DM_OFF + t] / (n + 1e-6f)) / (r + 1.0f);
        float sn = 0.0f;
        for (int c = 0; c < C; ++c) sn += ws[N_OFF + c];
        wv[t] = (sn > 0.0f) ? blended : tmf[t];
    }
    __syncthreads();
    if (t == 0) {
        float mn = wv[0], mx = wv[0];
        for (int c = 1; c < C; ++c) { mn = fminf(mn, wv[c]); mx = fmaxf(mx, wv[c]); }
        mm[0] = mn; mm[1] = mx;
    }
    __syncthreads();
    if (t < C) ws[NW_OFF + t] = (wv[t] - mm[0]) / (mm[1] - mm[0] + 1e-12f);
}

// ---------------- kernel 5: gather weight column ------------------------
__global__ void k_gather(const int* __restrict__ label, const float* __restrict__ ws,
                         float* __restrict__ out) {
    int s = blockIdx.x * 256 + threadIdx.x;
    out[(size_t)s * 22 + 21] = ws[NW_OFF + label[s]];
}

extern "C" void kernel_launch(void* const* d_in, const int* in_sizes, int n_in,
                              void* d_out, int out_size, void* d_ws, size_t ws_size,
                              hipStream_t stream) {
    const float* src   = (const float*)d_in[0];
    const float* tgt   = (const float*)d_in[1];
    const float* W     = (const float*)d_in[2];
    const float* b     = (const float*)d_in[3];
    const int*   label = (const int*)d_in[4];
    const float* tmf   = (const float*)d_in[5];
    const float* rec   = (const float*)d_in[6];
    float* out = (float*)d_out;
    float* ws  = (float*)d_ws;

    k_prep<<<(C * DDIM + 255) / 256, 256, 0, stream>>>(W, ws);
    k_gemm<<<dim3(NROWS / RPB, KSPLIT), 256, 0, stream>>>(src, tgt, ws);
    k_phaseB<<<NROWS / 256, 256, 0, stream>>>(b, ws, out);
    k_final<<<1, 64, 0, stream>>>(tmf, rec, ws);
    k_gather<<<S_ROWS / 256, 256, 0, stream>>>(label, ws, out);
}

// Round 13
// 236.872 us; speedup vs baseline: 5.9404x; 5.9404x over previous
//
#include <hip/hip_runtime.h>

#define S_ROWS 16384
#define T_ROWS 32768
#define NROWS  49152
#define DDIM   4096
#define C      21
#define KSPLIT 2
#define RPB    192                     // rows per block (64 lanes x 3 rows/lane)

// workspace layout (in floats)
#define WT_OFF 0
#define WT_SZ  (C * DDIM)              // 86016: W transposed to [C][D]
#define P_OFF  (WT_OFF + WT_SZ)
#define P_SLOT (NROWS * C)             // 1032192 per k-slot
#define DM_OFF (P_OFF + KSPLIT * P_SLOT)
#define N_OFF  (DM_OFF + C)
#define NW_OFF (N_OFF + C)

// LDS layout for k_gemm (floats): double-buffered X + W tiles, TILE_K=16
// X tile: 192 rows x 16 k = 3072 floats; W tile: 32 rows x 16 = 512 floats
#define XB0 0
#define XB1 3072
#define WB0 6144
#define WB1 (6144 + 512)
#define SMEM_FL 7168                   // 28672 B; reduction needs 5376 fl

// ---------------- kernel 1: transpose W, zero accumulators ----------------
__global__ void k_prep(const float* __restrict__ W, float* __restrict__ ws) {
    int idx = blockIdx.x * 256 + threadIdx.x;
    if (idx < C * DDIM) {
        int c = idx / DDIM, d = idx - c * DDIM;
        ws[WT_OFF + idx] = W[d * C + c];
    }
    if (blockIdx.x == 0 && threadIdx.x < 2 * C) {
        ws[DM_OFF + threadIdx.x] = 0.0f;   // zeroes delta_margin[21] + num[21]
    }
}

// async 16B global->LDS DMA (zero VGPR round-trip; lds dest = wave base + lane*16)
typedef const __attribute__((address_space(1))) void* gas_ptr;
typedef __attribute__((address_space(3))) void* las_ptr;
__device__ __forceinline__ void gload_lds16(const float* g, float* l) {
    __builtin_amdgcn_global_load_lds((gas_ptr)g, (las_ptr)l, 16, 0, 0);
}

// ---------------- kernel 2: tiled GEMM partials -------------------------
// block: 256 threads = 4 waves; 192 rows/block; grid (256 row-groups, 2 k-chunks)
// = 512 blocks = EXACTLY 2 blocks/CU, one round, ZERO TAIL.
// TILE_K=16: wave w owns the 4-wide k-slot w of each 16-wide k-tile; lane l
// owns rows l, l+64, l+128. acc[3][21] in registers; W broadcast from LDS.
//
// HISTORY / DISCIPLINE (12 rounds of evidence):
//  - REGISTER RULE (confirmed 3x: R0/R1, R12): acc[4][21]=84 under
//    launch_bounds(256,3) SPILLS (VGPR=84 + GB-scale WRITE_SIZE). The proven
//    no-spill pairs: acc[4][21]@(256,2), acc[2][21]@(256,3). This kernel:
//    acc[3][21]=63 @ (256,2) -- huge margin.
//  - SHAPE RULE: exact rounds + >=2 waves/SIMD. R5 (3/CU exact) ran AT model;
//    R9 (1/CU = 1 wave/SIMD) was 5x model; R4/R11's "2/CU" grids were really
//    1.5 ROUNDS -- their 256-block tail ran at 1 block/CU and dominated
//    (64 iters x 5.6us ~= R4's whole 370us). This grid: 512 = 2/CU exact,
//    8 waves/CU = 2 waves/SIMD, no tail.
//  - W AMORTIZATION (R6 model, validated by R5~=LDS-model): broadcast W b128
//    reads dominate LDS time; reads/FMA falls with rows/lane. R=3 gives
//    24 reads / 252 FMA insts per wave-iter (1.44x better than R5).
//    Per-CU-iter (2 blocks): HBM 26.6KB=1.08us > LDS 0.96 > VALU 0.42
//    -> HBM-bound ~138us over 128 iters.
//  - R6: counted-vmcnt NULL when latency is covered -> depth-1 __syncthreads
//    dbuf. R7: W-via-global regresses (L2 latency chains). R10: 512-thread
//    blocks spill. All avoided here.
//  - XOR swizzle for 16-fl rows (rule 21 both-sides, correctness-proven in
//    R12): physical slot = logical ^ ((row>>1)&3). DMA source pre-XORs
//    (l&3)^((l>>3)&3) (same 64B row-segment per 4-lane quad -> coalesced);
//    compute reads slot w ^ ((l>>1)&3). Involution verified both directions.
//  - src/tgt selected PER 16-ROW DMA GROUP (R8 lesson): 16-aligned ranges
//    (rg0=g*192, w*48, i*16 all multiples of 16) cannot straddle the
//    16384 boundary.
__launch_bounds__(256, 2)
__global__ void k_gemm(const float* __restrict__ src, const float* __restrict__ tgt,
                       float* __restrict__ ws) {
    __shared__ float smem[SMEM_FL];
    const int tid = threadIdx.x;
    const int g   = blockIdx.x;             // row group (192 rows)
    const int ks  = blockIdx.y;             // k chunk (2048 d)
    const int l   = tid & 63, w = tid >> 6;
    const int rg0 = g * RPB;
    const float* wt = ws + WT_OFF;

    // X DMA: 3 ops/wave, op i covers 16 rows starting at w*48 + i*16.
    // lane l -> local row l>>2, slot l&3; source pre-swizzled by (l>>3)&3.
    const int rr  = l >> 2, s4 = l & 3;
    const int fsw = ((s4 ^ ((l >> 3) & 3)) << 2);   // float offset in row
    const float* xg[3];
#pragma unroll
    for (int i = 0; i < 3; ++i) {
        const int grow = rg0 + w * 48 + i * 16;     // 16-row group start
        const float* bp = (grow < S_ROWS)
            ? (src + (size_t)grow * DDIM)
            : (tgt + (size_t)(grow - S_ROWS) * DDIM);
        xg[i] = bp + (size_t)rr * DDIM + ks * 2048 + fsw;
    }
    // W DMA: waves 0,1 each stage 16 rows (rows 21..31 read harmless ws bytes)
    const float* wg = wt + (size_t)(w * 16 + rr) * DDIM + ks * 2048 + (s4 << 2);

    float acc[3][C];
#pragma unroll
    for (int r = 0; r < 3; ++r)
#pragma unroll
        for (int c = 0; c < C; ++c) acc[r][c] = 0.0f;

    // prologue: stage tile 0 into buffer 0
#pragma unroll
    for (int i = 0; i < 3; ++i)
        gload_lds16(xg[i], &smem[XB0 + (w * 48 + i * 16) * 16]);
    if (w < 2) gload_lds16(wg, &smem[WB0 + w * 256]);
    __syncthreads();

    // hoisted compute-read constants
    const int xslot = (w ^ ((l >> 1) & 3)) << 2;    // swizzled slot, lane-const
    const int xbase = l * 16 + xslot;
    const int wslot = w << 2;

#pragma unroll 1
    for (int t = 0; t < 128; ++t) {
        const int xcur = (t & 1) ? XB1 : XB0;
        const int wcur = (t & 1) ? WB1 : WB0;
        // issue DMA for tile t+1 into the other buffer (flies under compute;
        // 2 staggered blocks/CU keep HBM busy through each block's drain)
        if (t < 127) {
            const int xnxt = (t & 1) ? XB0 : XB1;
            const int wnxt = (t & 1) ? WB0 : WB1;
            const int koff = (t + 1) * 16;
#pragma unroll
            for (int i = 0; i < 3; ++i)
                gload_lds16(xg[i] + koff, &smem[xnxt + (w * 48 + i * 16) * 16]);
            if (w < 2) gload_lds16(wg + koff, &smem[wnxt + w * 256]);
        }

        // single 4-wide pass: this wave's k-slot is w
        float4 xr[3];
#pragma unroll
        for (int r = 0; r < 3; ++r)
            xr[r] = *(const float4*)&smem[xcur + xbase + r * 1024];
#pragma unroll
        for (int c = 0; c < C; ++c) {
            float4 wv = *(const float4*)&smem[wcur + c * 16 + wslot];
#pragma unroll
            for (int r = 0; r < 3; ++r) {
                acc[r][c] += xr[r].x * wv.x + xr[r].y * wv.y +
                             xr[r].z * wv.z + xr[r].w * wv.w;
            }
        }
        __syncthreads();   // drains DMA vmcnt + lgkm; one barrier per iter
    }

    // cross-wave reduction: three sub-phases of 64 rows (5376 fl each);
    // h statically unrolled so acc stays register-indexed (rule #20)
    float* pout = ws + P_OFF + (size_t)ks * P_SLOT;
#pragma unroll
    for (int h = 0; h < 3; ++h) {
#pragma unroll
        for (int c = 0; c < C; ++c)
            smem[w * 1344 + l * 21 + c] = acc[h][c];
        __syncthreads();
        for (int idx = tid; idx < 1344; idx += 256) {
            int row = idx / 21, c = idx - row * 21;
            float s = smem[row * 21 + c] + smem[1344 + row * 21 + c] +
                      smem[2688 + row * 21 + c] + smem[4032 + row * 21 + c];
            pout[(size_t)(rg0 + h * 64 + row) * 21 + c] = s;
        }
        __syncthreads();
    }
}

// ---------------- kernel 3: sum partials, softmax, stats ----------------
__global__ void k_phaseB(const float* __restrict__ b_cls, float* __restrict__ ws,
                         float* __restrict__ out) {
    const int tid = threadIdx.x;
    const int row = blockIdx.x * 256 + tid;
    const float* P = ws + P_OFF;
    float lg[C];
#pragma unroll
    for (int c = 0; c < C; ++c) lg[c] = b_cls[c];
    for (int k = 0; k < KSPLIT; ++k) {
        const float* p = P + (size_t)k * P_SLOT + (size_t)row * C;
#pragma unroll
        for (int c = 0; c < C; ++c) lg[c] += p[c];
    }
    float m = lg[0];
#pragma unroll
    for (int c = 1; c < C; ++c) m = fmaxf(m, lg[c]);
    float e[C], s = 0.0f;
#pragma unroll
    for (int c = 0; c < C; ++c) { e[c] = __expf(lg[c] - m); s += e[c]; }
    float inv = 1.0f / s;

    if (row < S_ROWS) {                    // block-uniform branch (64 src blocks)
        float* o = out + (size_t)row * 22;
#pragma unroll
        for (int c = 0; c < C; ++c) o[c] = e[c] * inv;
    } else {
        __shared__ float s_dm[C], s_n[C];
        if (tid < C) { s_dm[tid] = 0.0f; s_n[tid] = 0.0f; }
        __syncthreads();
        float top = -1.0f, sum = 0.0f; int arg = 0;
#pragma unroll
        for (int c = 0; c < C; ++c) {
            float p = e[c] * inv; sum += p;
            if (p > top) { top = p; arg = c; }   // strict > keeps first argmax
        }
        float margin = top - (sum - top) * (1.0f / (C - 1));
        if (arg != 0) {
            atomicAdd(&s_dm[arg], margin);
            atomicAdd(&s_n[arg], 1.0f);
        }
        __syncthreads();
        if (tid < C) {
            atomicAdd(&ws[DM_OFF + tid], s_dm[tid]);
            atomicAdd(&ws[N_OFF + tid], s_n[tid]);
        }
    }
}

// ---------------- kernel 4: blend + minmax normalize (1 block) ----------
__global__ void k_final(const float* __restrict__ tmf, const float* __restrict__ rec,
                        float* __restrict__ ws) {
    __shared__ float wv[C];
    __shared__ float mm[2];
    const int t = threadIdx.x;
    if (t < C) {
        float r = rec[0];
        float n = ws[N_OFF + t];
        float blended = (tmf[t] * r + ws[DM_OFF + t] / (n + 1e-6f)) / (r + 1.0f);
        float sn = 0.0f;
        for (int c = 0; c < C; ++c) sn += ws[N_OFF + c];
        wv[t] = (sn > 0.0f) ? blended : tmf[t];
    }
    __syncthreads();
    if (t == 0) {
        float mn = wv[0], mx = wv[0];
        for (int c = 1; c < C; ++c) { mn = fminf(mn, wv[c]); mx = fmaxf(mx, wv[c]); }
        mm[0] = mn; mm[1] = mx;
    }
    __syncthreads();
    if (t < C) ws[NW_OFF + t] = (wv[t] - mm[0]) / (mm[1] - mm[0] + 1e-12f);
}

// ---------------- kernel 5: gather weight column ------------------------
__global__ void k_gather(const int* __restrict__ label, const float* __restrict__ ws,
                         float* __restrict__ out) {
    int s = blockIdx.x * 256 + threadIdx.x;
    out[(size_t)s * 22 + 21] = ws[NW_OFF + label[s]];
}

extern "C" void kernel_launch(void* const* d_in, const int* in_sizes, int n_in,
                              void* d_out, int out_size, void* d_ws, size_t ws_size,
                              hipStream_t stream) {
    const float* src   = (const float*)d_in[0];
    const float* tgt   = (const float*)d_in[1];
    const float* W     = (const float*)d_in[2];
    const float* b     = (const float*)d_in[3];
    const int*   label = (const int*)d_in[4];
    const float* tmf   = (const float*)d_in[5];
    const float* rec   = (const float*)d_in[6];
    float* out = (float*)d_out;
    float* ws  = (float*)d_ws;

    k_prep<<<(C * DDIM + 255) / 256, 256, 0, stream>>>(W, ws);
    k_gemm<<<dim3(NROWS / RPB, KSPLIT), 256, 0, stream>>>(src, tgt, ws);
    k_phaseB<<<NROWS / 256, 256, 0, stream>>>(b, ws, out);
    k_final<<<1, 64, 0, stream>>>(tmf, rec, ws);
    k_gather<<<S_ROWS / 256, 256, 0, stream>>>(label, ws, out);
}